// Round 9
// baseline (55.720 us; speedup 1.0000x reference)
//
#include <hip/hip_runtime.h>
#include <hip/hip_bf16.h>

typedef __attribute__((ext_vector_type(4))) float f32x4;

typedef const __attribute__((address_space(1))) void* gptr_t;
typedef __attribute__((address_space(3))) void* lptr_t;

#define NROW 8192
#define DDIM 256
#define HALF_B 4096
#define NB 64                        // 8192/128 tile bands
#define NTILES (NB * (NB + 1) / 2)   // 2080 upper-triangle tiles

// exp(dot/T) = exp2(dot * log2(e)/T), T = 0.07
#define E2SCALE 20.6099291555566196f
#define INV_T   14.2857142857142858f

// ---------------- kernel 1: normalize + fp8(e4m3) quant, swizzled layout ----
// Element (row,k), k = kc*32 + g*8 + o  (kc<8, g<4, o<8) stored at byte
//   row*256 + g*8 + ((kc ^ (row&7))<<5) + o
// so MFMA-fragment ds_read_b64 (lane: row=l&15, k-group g=l>>4) is bank-spread
// and global_load_lds can stage rows LINEARLY (swizzle baked into layout).
__global__ __launch_bounds__(256) void normalize_kernel(
    const float* __restrict__ z_i, const float* __restrict__ z_j,
    unsigned char* __restrict__ zn, float* __restrict__ lacc,
    unsigned int* __restrict__ counter) {
  const int lane = threadIdx.x & 63;
  const int w = blockIdx.x * 4 + (threadIdx.x >> 6);  // wave id 0..2047
  for (int row = w; row < NROW; row += 2048) {
    const float* src = (row < HALF_B) ? (z_i + (size_t)row * DDIM)
                                      : (z_j + (size_t)(row - HALF_B) * DDIM);
    float4 v = *reinterpret_cast<const float4*>(src + lane * 4);
    float ss = v.x * v.x + v.y * v.y + v.z * v.z + v.w * v.w;
#pragma unroll
    for (int m = 32; m; m >>= 1) ss += __shfl_xor(ss, m);
    const float inv = 1.0f / sqrtf(ss);
    // HW cvt to OCP e4m3 (RNE): bytes [x,y,z,w]
    int pk = __builtin_amdgcn_cvt_pk_fp8_f32(v.x * inv, v.y * inv, 0, false);
    pk = __builtin_amdgcn_cvt_pk_fp8_f32(v.z * inv, v.w * inv, pk, true);
    // k = lane*4 -> kc = lane>>3, g = (lane>>1)&3, o = (lane&1)*4
    const int kc = lane >> 3, g = (lane >> 1) & 3, hb = (lane & 1) * 4;
    const int p = g * 8 + ((kc ^ (row & 7)) << 5) + hb;
    *reinterpret_cast<unsigned int*>(zn + (size_t)row * DDIM + p) =
        (unsigned int)pk;
  }
  if (blockIdx.x == 0 && threadIdx.x == 0) { *lacc = 0.0f; *counter = 0u; }
}

// ---------------- kernel 2: upper-triangle 128x128 Gram tiles, fp8 ----------
// 512 thr = 8 waves (2 row x 4 col), wave-tile 64x32, acc[4][2].
// FULL-K staging: A(32KB)+B(32KB) staged once (rows contiguous in zn layout),
// ONE barrier, then 8 k-chunks of mfma_f32_16x16x32_fp8_fp8 straight through.
// LDS traffic per block: 64KB write + 192KB b64 reads (half of bf16 scheme).
// Epilogue = R8's scatter-store reduce (rowmat/colmat alias staging LDS).
__global__ __launch_bounds__(512, 4) void gram_kernel(
    const unsigned char* __restrict__ zn,
    float* __restrict__ P, float* __restrict__ pos) {
  __shared__ char smem[65536];         // A @0 (32K), B @32768 (32K)
  float (*rowmat)[68] = (float (*)[68])smem;            // 34816 B @0
  float (*colmat)[16] = (float (*)[16])(smem + 34816);  // 8192 B

  const int tid = threadIdx.x;
  const int lane = tid & 63;
  const int wid = tid >> 6;          // 0..7
  const int wr = wid >> 2;           // 0..1 (64 rows each)
  const int wc = wid & 3;            // 0..3 (32 cols each)

  int p = blockIdx.x;
  int by = 0;
  while (p >= NB - by) { p -= NB - by; ++by; }
  const int bx = by + p;
  const int rowBase = by * 128;
  const int colBase = bx * 128;
  const bool isdiag = (bx == by);
  const bool ispos = (bx - by == 32);

  // ---- stage full-K tiles: rows are contiguous 256-B runs in zn
#pragma unroll
  for (int i = 0; i < 4; ++i) {
    const unsigned char* ga = zn + (size_t)rowBase * DDIM + i * 8192 + tid * 16;
    const unsigned char* gb = zn + (size_t)colBase * DDIM + i * 8192 + tid * 16;
    __builtin_amdgcn_global_load_lds((gptr_t)ga,
        (lptr_t)(smem + i * 8192 + wid * 1024), 16, 0, 0);
    __builtin_amdgcn_global_load_lds((gptr_t)gb,
        (lptr_t)(smem + 32768 + i * 8192 + wid * 1024), 16, 0, 0);
  }
  __syncthreads();

  f32x4 acc[4][2] = {};
  const int r15 = lane & 15, g = lane >> 4, r7 = lane & 7;
  const char* Ab = smem;
  const char* Bb = smem + 32768;
  const int abase = (wr * 64 + r15) * 256;
  const int bbase = (wc * 32 + r15) * 256;
#pragma unroll
  for (int kc8 = 0; kc8 < 8; ++kc8) {
    const int off = g * 8 + ((kc8 ^ r7) << 5);
    long a0 = *reinterpret_cast<const long*>(Ab + abase + off);
    long a1 = *reinterpret_cast<const long*>(Ab + abase + 4096 + off);
    long a2 = *reinterpret_cast<const long*>(Ab + abase + 8192 + off);
    long a3 = *reinterpret_cast<const long*>(Ab + abase + 12288 + off);
    long b0 = *reinterpret_cast<const long*>(Bb + bbase + off);
    long b1 = *reinterpret_cast<const long*>(Bb + bbase + 4096 + off);
    acc[0][0] = __builtin_amdgcn_mfma_f32_16x16x32_fp8_fp8(a0, b0, acc[0][0], 0, 0, 0);
    acc[0][1] = __builtin_amdgcn_mfma_f32_16x16x32_fp8_fp8(a0, b1, acc[0][1], 0, 0, 0);
    acc[1][0] = __builtin_amdgcn_mfma_f32_16x16x32_fp8_fp8(a1, b0, acc[1][0], 0, 0, 0);
    acc[1][1] = __builtin_amdgcn_mfma_f32_16x16x32_fp8_fp8(a1, b1, acc[1][1], 0, 0, 0);
    acc[2][0] = __builtin_amdgcn_mfma_f32_16x16x32_fp8_fp8(a2, b0, acc[2][0], 0, 0, 0);
    acc[2][1] = __builtin_amdgcn_mfma_f32_16x16x32_fp8_fp8(a2, b1, acc[2][1], 0, 0, 0);
    acc[3][0] = __builtin_amdgcn_mfma_f32_16x16x32_fp8_fp8(a3, b0, acc[3][0], 0, 0, 0);
    acc[3][1] = __builtin_amdgcn_mfma_f32_16x16x32_fp8_fp8(a3, b1, acc[3][1], 0, 0, 0);
  }
  __syncthreads();   // staging reads done; LDS reused for reduce buffers

  // ---- epilogue phase 1: exp + scatter partials to LDS
  // C/D layout: col = lane&15, row = (lane>>4)*4 + v
  float colpart[2] = {0.0f, 0.0f};
#pragma unroll
  for (int m = 0; m < 4; ++m) {
#pragma unroll
    for (int v = 0; v < 4; ++v) {
      const int lrow = wr * 64 + m * 16 + (lane >> 4) * 4 + v;
      const int gi = rowBase + lrow;
      float rp = 0.0f;
#pragma unroll
      for (int n = 0; n < 2; ++n) {
        const float d = acc[m][n][v];
        float val = exp2f(d * E2SCALE);
        if (isdiag) {
          const int gj = colBase + wc * 32 + n * 16 + (lane & 15);
          if (gi == gj) val = 0.0f;           // exclude diagonal
        } else if (ispos) {
          const int gj = colBase + wc * 32 + n * 16 + (lane & 15);
          if (gj == gi + HALF_B) {            // positive pair
            const float pv = d * INV_T;
            pos[gi] = pv;
            pos[gj] = pv;
          }
        }
        rp += val;
        colpart[n] += val;
      }
      rowmat[lrow][wc * 16 + (lane & 15)] = rp;
    }
  }
  colmat[wc * 32 + (lane & 15)][wr * 4 + (lane >> 4)] = colpart[0];
  colmat[wc * 32 + 16 + (lane & 15)][wr * 4 + (lane >> 4)] = colpart[1];
  __syncthreads();

  // ---- epilogue phase 2: read-reduce + coalesced P stores
  {
    const int row = tid >> 2;          // 0..127
    const int seg = tid & 3;           // 0..3 (16 cols each)
    const float* rr = &rowmat[row][seg * 16];
    f32x4 a0 = *reinterpret_cast<const f32x4*>(rr);
    f32x4 a1 = *reinterpret_cast<const f32x4*>(rr + 4);
    f32x4 a2 = *reinterpret_cast<const f32x4*>(rr + 8);
    f32x4 a3 = *reinterpret_cast<const f32x4*>(rr + 12);
    f32x4 t4 = (a0 + a1) + (a2 + a3);
    float s = (t4[0] + t4[1]) + (t4[2] + t4[3]);
    s += __shfl_xor(s, 1);
    s += __shfl_xor(s, 2);
    if (seg == 0) P[(size_t)bx * NROW + rowBase + row] = s;
  }
  if (tid < 128 && !isdiag) {
    const float* cc = colmat[tid];
    f32x4 c0 = *reinterpret_cast<const f32x4*>(cc);
    f32x4 c1 = *reinterpret_cast<const f32x4*>(cc + 4);
    f32x4 c2 = *reinterpret_cast<const f32x4*>(cc + 8);
    f32x4 c3 = *reinterpret_cast<const f32x4*>(cc + 12);
    f32x4 t4 = (c0 + c1) + (c2 + c3);
    P[(size_t)by * NROW + colBase + tid] =
        (t4[0] + t4[1]) + (t4[2] + t4[3]);
  }
}

// -------- kernel 3: row reduction + log + fused finalize (arrival counter) --
__global__ __launch_bounds__(256) void rowreduce_kernel(
    const float* __restrict__ P, const float* __restrict__ pos,
    float* __restrict__ lacc, unsigned int* __restrict__ counter,
    float* __restrict__ out) {
  const int i = blockIdx.x * 256 + threadIdx.x;
  float s = 0.0f;
#pragma unroll 8
  for (int k = 0; k < NB; ++k) s += P[(size_t)k * NROW + i];
  float partial = logf(s) - pos[i];
#pragma unroll
  for (int m = 32; m; m >>= 1) partial += __shfl_xor(partial, m);
  __shared__ float sred[4];
  if ((threadIdx.x & 63) == 0) sred[threadIdx.x >> 6] = partial;
  __syncthreads();
  if (threadIdx.x == 0) {
    atomicAdd(lacc, sred[0] + sred[1] + sred[2] + sred[3]);
    __threadfence();
    const unsigned done = atomicAdd(counter, 1u);
    if (done == (unsigned)(gridDim.x - 1)) {      // last block finalizes
      const float v = atomicAdd(lacc, 0.0f);      // device-scope read
      out[0] = v * (1.0f / (float)NROW);
    }
  }
}

extern "C" void kernel_launch(void* const* d_in, const int* in_sizes, int n_in,
                              void* d_out, int out_size, void* d_ws, size_t ws_size,
                              hipStream_t stream) {
  const float* z_i = (const float*)d_in[0];
  const float* z_j = (const float*)d_in[1];
  float* out = (float*)d_out;

  char* ws = (char*)d_ws;
  unsigned char* zn = (unsigned char*)ws;                        // 2 MB fp8
  float* pos  = (float*)(ws + 2097152);                          // 32 KB
  float* P    = (float*)(ws + 2097152 + 32768);                  // 2 MB
  float* lacc = (float*)(ws + 2097152 + 32768 + 2097152);        // 4 B
  unsigned int* counter = (unsigned int*)(ws + 2097152 + 32768 + 2097152 + 4);

  normalize_kernel<<<512, 256, 0, stream>>>(z_i, z_j, zn, lacc, counter);
  gram_kernel<<<NTILES, 512, 0, stream>>>(zn, P, pos);
  rowreduce_kernel<<<NROW / 256, 256, 0, stream>>>(P, pos, lacc, counter, out);
}

// Round 10
// 45.216 us; speedup vs baseline: 1.2323x; 1.2323x over previous
//
#include <hip/hip_runtime.h>
#include <hip/hip_bf16.h>

typedef __attribute__((ext_vector_type(4))) float f32x4;
typedef __attribute__((ext_vector_type(2))) long i64x2;

typedef const __attribute__((address_space(1))) void* gptr_t;
typedef __attribute__((address_space(3))) void* lptr_t;

#define NROW 8192
#define DDIM 256
#define HALF_B 4096
#define NB 64                        // 8192/128 tile bands
#define NTILES (NB * (NB + 1) / 2)   // 2080 upper-triangle tiles

// exp(dot/T) = exp2(dot * log2(e)/T), T = 0.07
#define E2SCALE 20.6099291555566196f
#define INV_T   14.2857142857142858f

// ---------------- kernel 1: normalize + fp8(e4m3) quant, paired layout -----
// Element (row,k): kc = k>>5 (0..7), g = (k>>3)&3, o = k&7; p = kc>>1, e = kc&1.
// Stored byte = row*256 + (p>>1)*128 + ((((p&1)<<2)|g) ^ (row&7))*16 + e*8 + o.
// This reproduces the R2-R8 PROVEN zero-conflict ds_read_b128 granule algebra
// (granule = (half*4+g) ^ r7) while keeping global_load_lds rows linear.
__global__ __launch_bounds__(256) void normalize_kernel(
    const float* __restrict__ z_i, const float* __restrict__ z_j,
    unsigned char* __restrict__ zn, float* __restrict__ lacc,
    unsigned int* __restrict__ counter) {
  const int lane = threadIdx.x & 63;
  const int w = blockIdx.x * 4 + (threadIdx.x >> 6);  // wave id 0..2047
  // lane's dword: k0 = lane*4
  const int g  = (lane >> 1) & 3;
  const int e  = (lane >> 3) & 1;
  const int ph = (lane >> 4) & 1;     // p&1
  const int pq = lane >> 5;           // p>>1
  const int o  = (lane & 1) * 4;
  const int cbase = (ph << 2) | g;    // c before row-XOR (0..7)
  for (int row = w; row < NROW; row += 2048) {
    const float* src = (row < HALF_B) ? (z_i + (size_t)row * DDIM)
                                      : (z_j + (size_t)(row - HALF_B) * DDIM);
    float4 v = *reinterpret_cast<const float4*>(src + lane * 4);
    float ss = v.x * v.x + v.y * v.y + v.z * v.z + v.w * v.w;
#pragma unroll
    for (int m = 32; m; m >>= 1) ss += __shfl_xor(ss, m);
    const float inv = 1.0f / sqrtf(ss);
    int pk = __builtin_amdgcn_cvt_pk_fp8_f32(v.x * inv, v.y * inv, 0, false);
    pk = __builtin_amdgcn_cvt_pk_fp8_f32(v.z * inv, v.w * inv, pk, true);
    const int pos = pq * 128 + ((cbase ^ (row & 7)) << 4) + e * 8 + o;
    *reinterpret_cast<unsigned int*>(zn + (size_t)row * DDIM + pos) =
        (unsigned int)pk;
  }
  if (blockIdx.x == 0 && threadIdx.x == 0) { *lacc = 0.0f; *counter = 0u; }
}

// ---------------- kernel 2: upper-triangle 128x128 Gram tiles, fp8 ----------
// 512 thr = 8 waves (2 row x 4 col), wave-tile 64x32, acc[4][2].
// FULL-K staging: A(32KB)+B(32KB) once, then 4 k-pair steps, each:
//   6 x ds_read_b128 (A m=0..3, B n=0..1; each = {kc=2p, kc=2p+1} i64 ops)
//   16 x mfma_f32_16x16x32_fp8_fp8.
// Epilogue = R8's scatter-store reduce (rowmat/colmat alias staging LDS).
__global__ __launch_bounds__(512, 4) void gram_kernel(
    const unsigned char* __restrict__ zn,
    float* __restrict__ P, float* __restrict__ pos) {
  __shared__ char smem[65536];         // A @0 (32K), B @32768 (32K)
  float (*rowmat)[68] = (float (*)[68])smem;            // 34816 B @0
  float (*colmat)[16] = (float (*)[16])(smem + 34816);  // 8192 B

  const int tid = threadIdx.x;
  const int lane = tid & 63;
  const int wid = tid >> 6;          // 0..7
  const int wr = wid >> 2;           // 0..1 (64 rows each)
  const int wc = wid & 3;            // 0..3 (32 cols each)

  int p = blockIdx.x;
  int by = 0;
  while (p >= NB - by) { p -= NB - by; ++by; }
  const int bx = by + p;
  const int rowBase = by * 128;
  const int colBase = bx * 128;
  const bool isdiag = (bx == by);
  const bool ispos = (bx - by == 32);

  // ---- stage full-K tiles: zn rows are contiguous 256-B runs (swizzle baked)
#pragma unroll
  for (int i = 0; i < 4; ++i) {
    const unsigned char* ga = zn + (size_t)rowBase * DDIM + i * 8192 + tid * 16;
    const unsigned char* gb = zn + (size_t)colBase * DDIM + i * 8192 + tid * 16;
    __builtin_amdgcn_global_load_lds((gptr_t)ga,
        (lptr_t)(smem + i * 8192 + wid * 1024), 16, 0, 0);
    __builtin_amdgcn_global_load_lds((gptr_t)gb,
        (lptr_t)(smem + 32768 + i * 8192 + wid * 1024), 16, 0, 0);
  }
  __syncthreads();

  f32x4 acc[4][2] = {};
  const int r15 = lane & 15, g = lane >> 4, r7 = lane & 7;
  const char* Ab = smem;
  const char* Bb = smem + 32768;
  const int abase = (wr * 64 + r15) * 256;
  const int bbase = (wc * 32 + r15) * 256;
#pragma unroll
  for (int kp = 0; kp < 4; ++kp) {   // k-pair: kc = 2kp, 2kp+1
    const int off = (kp >> 1) * 128 + (((((kp & 1) << 2) | g) ^ r7) << 4);
    i64x2 A0 = *reinterpret_cast<const i64x2*>(Ab + abase + off);
    i64x2 A1 = *reinterpret_cast<const i64x2*>(Ab + abase + 4096 + off);
    i64x2 A2 = *reinterpret_cast<const i64x2*>(Ab + abase + 8192 + off);
    i64x2 A3 = *reinterpret_cast<const i64x2*>(Ab + abase + 12288 + off);
    i64x2 B0 = *reinterpret_cast<const i64x2*>(Bb + bbase + off);
    i64x2 B1 = *reinterpret_cast<const i64x2*>(Bb + bbase + 4096 + off);
#pragma unroll
    for (int e = 0; e < 2; ++e) {
      const long a0 = A0[e], a1 = A1[e], a2 = A2[e], a3 = A3[e];
      const long b0 = B0[e], b1 = B1[e];
      acc[0][0] = __builtin_amdgcn_mfma_f32_16x16x32_fp8_fp8(a0, b0, acc[0][0], 0, 0, 0);
      acc[0][1] = __builtin_amdgcn_mfma_f32_16x16x32_fp8_fp8(a0, b1, acc[0][1], 0, 0, 0);
      acc[1][0] = __builtin_amdgcn_mfma_f32_16x16x32_fp8_fp8(a1, b0, acc[1][0], 0, 0, 0);
      acc[1][1] = __builtin_amdgcn_mfma_f32_16x16x32_fp8_fp8(a1, b1, acc[1][1], 0, 0, 0);
      acc[2][0] = __builtin_amdgcn_mfma_f32_16x16x32_fp8_fp8(a2, b0, acc[2][0], 0, 0, 0);
      acc[2][1] = __builtin_amdgcn_mfma_f32_16x16x32_fp8_fp8(a2, b1, acc[2][1], 0, 0, 0);
      acc[3][0] = __builtin_amdgcn_mfma_f32_16x16x32_fp8_fp8(a3, b0, acc[3][0], 0, 0, 0);
      acc[3][1] = __builtin_amdgcn_mfma_f32_16x16x32_fp8_fp8(a3, b1, acc[3][1], 0, 0, 0);
    }
  }
  __syncthreads();   // staging reads done; LDS reused for reduce buffers

  // ---- epilogue phase 1: exp + scatter partials to LDS
  // C/D layout: col = lane&15, row = (lane>>4)*4 + v
  float colpart[2] = {0.0f, 0.0f};
#pragma unroll
  for (int m = 0; m < 4; ++m) {
#pragma unroll
    for (int v = 0; v < 4; ++v) {
      const int lrow = wr * 64 + m * 16 + (lane >> 4) * 4 + v;
      const int gi = rowBase + lrow;
      float rp = 0.0f;
#pragma unroll
      for (int n = 0; n < 2; ++n) {
        const float d = acc[m][n][v];
        float val = exp2f(d * E2SCALE);
        if (isdiag) {
          const int gj = colBase + wc * 32 + n * 16 + (lane & 15);
          if (gi == gj) val = 0.0f;           // exclude diagonal
        } else if (ispos) {
          const int gj = colBase + wc * 32 + n * 16 + (lane & 15);
          if (gj == gi + HALF_B) {            // positive pair
            const float pv = d * INV_T;
            pos[gi] = pv;
            pos[gj] = pv;
          }
        }
        rp += val;
        colpart[n] += val;
      }
      rowmat[lrow][wc * 16 + (lane & 15)] = rp;
    }
  }
  colmat[wc * 32 + (lane & 15)][wr * 4 + (lane >> 4)] = colpart[0];
  colmat[wc * 32 + 16 + (lane & 15)][wr * 4 + (lane >> 4)] = colpart[1];
  __syncthreads();

  // ---- epilogue phase 2: read-reduce + coalesced P stores
  {
    const int row = tid >> 2;          // 0..127
    const int seg = tid & 3;           // 0..3 (16 cols each)
    const float* rr = &rowmat[row][seg * 16];
    f32x4 a0 = *reinterpret_cast<const f32x4*>(rr);
    f32x4 a1 = *reinterpret_cast<const f32x4*>(rr + 4);
    f32x4 a2 = *reinterpret_cast<const f32x4*>(rr + 8);
    f32x4 a3 = *reinterpret_cast<const f32x4*>(rr + 12);
    f32x4 t4 = (a0 + a1) + (a2 + a3);
    float s = (t4[0] + t4[1]) + (t4[2] + t4[3]);
    s += __shfl_xor(s, 1);
    s += __shfl_xor(s, 2);
    if (seg == 0) P[(size_t)bx * NROW + rowBase + row] = s;
  }
  if (tid < 128 && !isdiag) {
    const float* cc = colmat[tid];
    f32x4 c0 = *reinterpret_cast<const f32x4*>(cc);
    f32x4 c1 = *reinterpret_cast<const f32x4*>(cc + 4);
    f32x4 c2 = *reinterpret_cast<const f32x4*>(cc + 8);
    f32x4 c3 = *reinterpret_cast<const f32x4*>(cc + 12);
    f32x4 t4 = (c0 + c1) + (c2 + c3);
    P[(size_t)by * NROW + colBase + tid] =
        (t4[0] + t4[1]) + (t4[2] + t4[3]);
  }
}

// -------- kernel 3: row reduction + log + fused finalize (arrival counter) --
__global__ __launch_bounds__(256) void rowreduce_kernel(
    const float* __restrict__ P, const float* __restrict__ pos,
    float* __restrict__ lacc, unsigned int* __restrict__ counter,
    float* __restrict__ out) {
  const int i = blockIdx.x * 256 + threadIdx.x;
  float s = 0.0f;
#pragma unroll 8
  for (int k = 0; k < NB; ++k) s += P[(size_t)k * NROW + i];
  float partial = logf(s) - pos[i];
#pragma unroll
  for (int m = 32; m; m >>= 1) partial += __shfl_xor(partial, m);
  __shared__ float sred[4];
  if ((threadIdx.x & 63) == 0) sred[threadIdx.x >> 6] = partial;
  __syncthreads();
  if (threadIdx.x == 0) {
    atomicAdd(lacc, sred[0] + sred[1] + sred[2] + sred[3]);
    __threadfence();
    const unsigned done = atomicAdd(counter, 1u);
    if (done == (unsigned)(gridDim.x - 1)) {      // last block finalizes
      const float v = atomicAdd(lacc, 0.0f);      // device-scope read
      out[0] = v * (1.0f / (float)NROW);
    }
  }
}

extern "C" void kernel_launch(void* const* d_in, const int* in_sizes, int n_in,
                              void* d_out, int out_size, void* d_ws, size_t ws_size,
                              hipStream_t stream) {
  const float* z_i = (const float*)d_in[0];
  const float* z_j = (const float*)d_in[1];
  float* out = (float*)d_out;

  char* ws = (char*)d_ws;
  unsigned char* zn = (unsigned char*)ws;                        // 2 MB fp8
  float* pos  = (float*)(ws + 2097152);                          // 32 KB
  float* P    = (float*)(ws + 2097152 + 32768);                  // 2 MB
  float* lacc = (float*)(ws + 2097152 + 32768 + 2097152);        // 4 B
  unsigned int* counter = (unsigned int*)(ws + 2097152 + 32768 + 2097152 + 4);

  normalize_kernel<<<512, 256, 0, stream>>>(z_i, z_j, zn, lacc, counter);
  gram_kernel<<<NTILES, 512, 0, stream>>>(zn, P, pos);
  rowreduce_kernel<<<NROW / 256, 256, 0, stream>>>(P, pos, lacc, counter, out);
}

// Round 14
// 42.085 us; speedup vs baseline: 1.3240x; 1.0744x over previous
//
#include <hip/hip_runtime.h>
#include <hip/hip_bf16.h>

typedef __attribute__((ext_vector_type(4))) float f32x4;
typedef __attribute__((ext_vector_type(2))) long i64x2;

typedef const __attribute__((address_space(1))) void* gptr_t;
typedef __attribute__((address_space(3))) void* lptr_t;

#define NROW 8192
#define DDIM 256
#define HALF_B 4096
#define NB 64                        // 8192/128 tile bands
#define NTILES (NB * (NB + 1) / 2)   // 2080 upper-triangle tiles

// exp(dot/T) = exp2(dot * log2(e)/T), T = 0.07
#define E2SCALE 20.6099291555566196f
#define INV_T   14.2857142857142858f

__device__ __forceinline__ float fast_exp2(float x) {
  float r;
  asm("v_exp_f32 %0, %1" : "=v"(r) : "v"(x));
  return r;
}

// ---------------- kernel 1: normalize + fp8(e4m3) quant, paired layout -----
// Element (row,k): kc = k>>5 (0..7), g = (k>>3)&3, o = k&7; p = kc>>1, e = kc&1.
// Stored byte = row*256 + (p>>1)*128 + ((((p&1)<<2)|g) ^ (row&7))*16 + e*8 + o.
// K-halves (p>>1 = 0/1) are contiguous 128-B runs per row -> half-K staging
// stays linear for global_load_lds; ds_read granule algebra = R2-R8 proven
// zero-conflict pattern. (Unchanged from R10 — passed, absmax 0.)
__global__ __launch_bounds__(256) void normalize_kernel(
    const float* __restrict__ z_i, const float* __restrict__ z_j,
    unsigned char* __restrict__ zn, float* __restrict__ lacc,
    unsigned int* __restrict__ counter) {
  const int lane = threadIdx.x & 63;
  const int w = blockIdx.x * 4 + (threadIdx.x >> 6);  // wave id 0..2047
  const int g  = (lane >> 1) & 3;
  const int e  = (lane >> 3) & 1;
  const int ph = (lane >> 4) & 1;     // p&1
  const int pq = lane >> 5;           // p>>1
  const int o  = (lane & 1) * 4;
  const int cbase = (ph << 2) | g;
  for (int row = w; row < NROW; row += 2048) {
    const float* src = (row < HALF_B) ? (z_i + (size_t)row * DDIM)
                                      : (z_j + (size_t)(row - HALF_B) * DDIM);
    float4 v = *reinterpret_cast<const float4*>(src + lane * 4);
    float ss = v.x * v.x + v.y * v.y + v.z * v.z + v.w * v.w;
#pragma unroll
    for (int m = 32; m; m >>= 1) ss += __shfl_xor(ss, m);
    const float inv = 1.0f / sqrtf(ss);
    int pk = __builtin_amdgcn_cvt_pk_fp8_f32(v.x * inv, v.y * inv, 0, false);
    pk = __builtin_amdgcn_cvt_pk_fp8_f32(v.z * inv, v.w * inv, pk, true);
    const int pos = pq * 128 + ((cbase ^ (row & 7)) << 4) + e * 8 + o;
    *reinterpret_cast<unsigned int*>(zn + (size_t)row * DDIM + pos) =
        (unsigned int)pk;
  }
  if (blockIdx.x == 0 && threadIdx.x == 0) { *lacc = 0.0f; *counter = 0u; }
}

// ---------------- kernel 2: upper-triangle 128x128 Gram tiles, fp8 ----------
// 512 thr = 8 waves (2 row x 4 col), wave-tile 64x32, acc[4][2].
// T4 counted-vmcnt pipeline: issue ALL 8 stage loads (half0's 4 first),
// s_waitcnt vmcnt(4) + barrier -> compute half0 while half1 in flight,
// vmcnt(0) + barrier -> compute half1. LDS: A0,A1,B0,B1 16KB each.
// Epilogue: scatter-store reduce (R8), exp via raw v_exp_f32.
__global__ __launch_bounds__(512, 4) void gram_kernel(
    const unsigned char* __restrict__ zn,
    float* __restrict__ P, float* __restrict__ pos) {
  __shared__ char smem[65536];         // A0@0 A1@16K B0@32K B1@48K
  float (*rowmat)[68] = (float (*)[68])smem;            // 34816 B @0
  float (*colmat)[16] = (float (*)[16])(smem + 34816);  // 8192 B

  const int tid = threadIdx.x;
  const int lane = tid & 63;
  const int wid = tid >> 6;          // 0..7
  const int wr = wid >> 2;           // 0..1 (64 rows each)
  const int wc = wid & 3;            // 0..3 (32 cols each)

  int p = blockIdx.x;
  int by = 0;
  while (p >= NB - by) { p -= NB - by; ++by; }
  const int bx = by + p;
  const int rowBase = by * 128;
  const int colBase = bx * 128;
  const bool isdiag = (bx == by);
  const bool ispos = (bx - by == 32);

  const int rloc = tid >> 3;
  const int c16 = (tid & 7) * 16;

  // ---- issue all 8 stage loads; half-0's 4 first (vmcnt counting order)
#pragma unroll
  for (int h = 0; h < 2; ++h) {
#pragma unroll
    for (int t = 0; t < 2; ++t) {
      const int r = t * 64 + rloc;
      const unsigned char* ga =
          zn + (size_t)(rowBase + r) * DDIM + h * 128 + c16;
      const unsigned char* gb =
          zn + (size_t)(colBase + r) * DDIM + h * 128 + c16;
      __builtin_amdgcn_global_load_lds((gptr_t)ga,
          (lptr_t)(smem + h * 16384 + t * 8192 + wid * 1024), 16, 0, 0);
      __builtin_amdgcn_global_load_lds((gptr_t)gb,
          (lptr_t)(smem + 32768 + h * 16384 + t * 8192 + wid * 1024), 16, 0, 0);
    }
  }

  f32x4 acc[4][2] = {};
  const int r15 = lane & 15, g = lane >> 4, r7 = lane & 7;
  const int abase = (wr * 64 + r15) * 128;   // 128-B rows within half-buffer
  const int bbase = (wc * 32 + r15) * 128;

  // half-0 ready (own wave's first 4 loads done), half-1 still in flight
  asm volatile("s_waitcnt vmcnt(4)" ::: "memory");
  __builtin_amdgcn_s_barrier();
  __builtin_amdgcn_sched_barrier(0);

#pragma unroll
  for (int h = 0; h < 2; ++h) {
    if (h == 1) {
      asm volatile("s_waitcnt vmcnt(0)" ::: "memory");
      __builtin_amdgcn_s_barrier();
      __builtin_amdgcn_sched_barrier(0);
    }
    const char* Ab = reinterpret_cast<const char*>(smem) + h * 16384;
    const char* Bb = reinterpret_cast<const char*>(smem) + 32768 + h * 16384;
#pragma unroll
    for (int lp = 0; lp < 2; ++lp) {   // local k-pair within half
      const int off = ((((lp << 2) | g) ^ r7) << 4);
      i64x2 A0 = *reinterpret_cast<const i64x2*>(Ab + abase + off);
      i64x2 A1 = *reinterpret_cast<const i64x2*>(Ab + abase + 2048 + off);
      i64x2 A2 = *reinterpret_cast<const i64x2*>(Ab + abase + 4096 + off);
      i64x2 A3 = *reinterpret_cast<const i64x2*>(Ab + abase + 6144 + off);
      i64x2 B0 = *reinterpret_cast<const i64x2*>(Bb + bbase + off);
      i64x2 B1 = *reinterpret_cast<const i64x2*>(Bb + bbase + 2048 + off);
#pragma unroll
      for (int e = 0; e < 2; ++e) {
        const long a0 = A0[e], a1 = A1[e], a2 = A2[e], a3 = A3[e];
        const long b0 = B0[e], b1 = B1[e];
        acc[0][0] = __builtin_amdgcn_mfma_f32_16x16x32_fp8_fp8(a0, b0, acc[0][0], 0, 0, 0);
        acc[0][1] = __builtin_amdgcn_mfma_f32_16x16x32_fp8_fp8(a0, b1, acc[0][1], 0, 0, 0);
        acc[1][0] = __builtin_amdgcn_mfma_f32_16x16x32_fp8_fp8(a1, b0, acc[1][0], 0, 0, 0);
        acc[1][1] = __builtin_amdgcn_mfma_f32_16x16x32_fp8_fp8(a1, b1, acc[1][1], 0, 0, 0);
        acc[2][0] = __builtin_amdgcn_mfma_f32_16x16x32_fp8_fp8(a2, b0, acc[2][0], 0, 0, 0);
        acc[2][1] = __builtin_amdgcn_mfma_f32_16x16x32_fp8_fp8(a2, b1, acc[2][1], 0, 0, 0);
        acc[3][0] = __builtin_amdgcn_mfma_f32_16x16x32_fp8_fp8(a3, b0, acc[3][0], 0, 0, 0);
        acc[3][1] = __builtin_amdgcn_mfma_f32_16x16x32_fp8_fp8(a3, b1, acc[3][1], 0, 0, 0);
      }
    }
  }
  __syncthreads();   // staging reads done; LDS reused for reduce buffers

  // ---- epilogue phase 1: exp + scatter partials to LDS
  // C/D layout: col = lane&15, row = (lane>>4)*4 + v
  float colpart[2] = {0.0f, 0.0f};
#pragma unroll
  for (int m = 0; m < 4; ++m) {
#pragma unroll
    for (int v = 0; v < 4; ++v) {
      const int lrow = wr * 64 + m * 16 + (lane >> 4) * 4 + v;
      const int gi = rowBase + lrow;
      float rp = 0.0f;
#pragma unroll
      for (int n = 0; n < 2; ++n) {
        const float d = acc[m][n][v];
        float val = fast_exp2(d * E2SCALE);
        if (isdiag) {
          const int gj = colBase + wc * 32 + n * 16 + (lane & 15);
          if (gi == gj) val = 0.0f;           // exclude diagonal
        } else if (ispos) {
          const int gj = colBase + wc * 32 + n * 16 + (lane & 15);
          if (gj == gi + HALF_B) {            // positive pair
            const float pv = d * INV_T;
            pos[gi] = pv;
            pos[gj] = pv;
          }
        }
        rp += val;
        colpart[n] += val;
      }
      rowmat[lrow][wc * 16 + (lane & 15)] = rp;
    }
  }
  colmat[wc * 32 + (lane & 15)][wr * 4 + (lane >> 4)] = colpart[0];
  colmat[wc * 32 + 16 + (lane & 15)][wr * 4 + (lane >> 4)] = colpart[1];
  __syncthreads();

  // ---- epilogue phase 2: read-reduce + coalesced P stores
  {
    const int row = tid >> 2;          // 0..127
    const int seg = tid & 3;           // 0..3 (16 cols each)
    const float* rr = &rowmat[row][seg * 16];
    f32x4 a0 = *reinterpret_cast<const f32x4*>(rr);
    f32x4 a1 = *reinterpret_cast<const f32x4*>(rr + 4);
    f32x4 a2 = *reinterpret_cast<const f32x4*>(rr + 8);
    f32x4 a3 = *reinterpret_cast<const f32x4*>(rr + 12);
    f32x4 t4 = (a0 + a1) + (a2 + a3);
    float s = (t4[0] + t4[1]) + (t4[2] + t4[3]);
    s += __shfl_xor(s, 1);
    s += __shfl_xor(s, 2);
    if (seg == 0) P[(size_t)bx * NROW + rowBase + row] = s;
  }
  if (tid < 128 && !isdiag) {
    const float* cc = colmat[tid];
    f32x4 c0 = *reinterpret_cast<const f32x4*>(cc);
    f32x4 c1 = *reinterpret_cast<const f32x4*>(cc + 4);
    f32x4 c2 = *reinterpret_cast<const f32x4*>(cc + 8);
    f32x4 c3 = *reinterpret_cast<const f32x4*>(cc + 12);
    f32x4 t4 = (c0 + c1) + (c2 + c3);
    P[(size_t)by * NROW + colBase + tid] =
        (t4[0] + t4[1]) + (t4[2] + t4[3]);
  }
}

// -------- kernel 3: row reduction + log + fused finalize (arrival counter) --
__global__ __launch_bounds__(256) void rowreduce_kernel(
    const float* __restrict__ P, const float* __restrict__ pos,
    float* __restrict__ lacc, unsigned int* __restrict__ counter,
    float* __restrict__ out) {
  const int i = blockIdx.x * 256 + threadIdx.x;
  float s = 0.0f;
#pragma unroll 8
  for (int k = 0; k < NB; ++k) s += P[(size_t)k * NROW + i];
  float partial = logf(s) - pos[i];
#pragma unroll
  for (int m = 32; m; m >>= 1) partial += __shfl_xor(partial, m);
  __shared__ float sred[4];
  if ((threadIdx.x & 63) == 0) sred[threadIdx.x >> 6] = partial;
  __syncthreads();
  if (threadIdx.x == 0) {
    atomicAdd(lacc, sred[0] + sred[1] + sred[2] + sred[3]);
    __threadfence();
    const unsigned done = atomicAdd(counter, 1u);
    if (done == (unsigned)(gridDim.x - 1)) {      // last block finalizes
      const float v = atomicAdd(lacc, 0.0f);      // device-scope read
      out[0] = v * (1.0f / (float)NROW);
    }
  }
}

extern "C" void kernel_launch(void* const* d_in, const int* in_sizes, int n_in,
                              void* d_out, int out_size, void* d_ws, size_t ws_size,
                              hipStream_t stream) {
  const float* z_i = (const float*)d_in[0];
  const float* z_j = (const float*)d_in[1];
  float* out = (float*)d_out;

  char* ws = (char*)d_ws;
  unsigned char* zn = (unsigned char*)ws;                        // 2 MB fp8
  float* pos  = (float*)(ws + 2097152);                          // 32 KB
  float* P    = (float*)(ws + 2097152 + 32768);                  // 2 MB
  float* lacc = (float*)(ws + 2097152 + 32768 + 2097152);        // 4 B
  unsigned int* counter = (unsigned int*)(ws + 2097152 + 32768 + 2097152 + 4);

  normalize_kernel<<<512, 256, 0, stream>>>(z_i, z_j, zn, lacc, counter);
  gram_kernel<<<NTILES, 512, 0, stream>>>(zn, P, pos);
  rowreduce_kernel<<<NROW / 256, 256, 0, stream>>>(P, pos, lacc, counter, out);
}